// Round 7
// baseline (302.962 us; speedup 1.0000x reference)
//
#include <hip/hip_runtime.h>
#include <hip/hip_bf16.h>

typedef __bf16 bf16x8 __attribute__((ext_vector_type(8)));
typedef __bf16 bf16x4 __attribute__((ext_vector_type(4)));
typedef float  f32x4  __attribute__((ext_vector_type(4)));

#define MFMA16(a, b, c) __builtin_amdgcn_mfma_f32_16x16x32_bf16((a), (b), (c), 0, 0, 0)

// Problem constants: B=8, N=1024, D=512, H=8, DH=64

// ---------------------------------------------------------------------------
// Kernel 1: fused QKV projection (unchanged).
// ---------------------------------------------------------------------------
__global__ __launch_bounds__(256) void gemm_qkv(
    const float* __restrict__ x,
    const float* __restrict__ Wq, const float* __restrict__ Wk,
    const float* __restrict__ Wv,
    __bf16* __restrict__ qo, __bf16* __restrict__ ko, __bf16* __restrict__ vto)
{
    __shared__ __bf16 As[64][40];
    __shared__ __bf16 Bs[64][40];
    const int tid  = threadIdx.x;
    const int lane = tid & 63;
    const int wid  = tid >> 6;
    const int g    = lane >> 4, l16 = lane & 15;
    const int wr   = wid >> 1,  wc  = wid & 1;
    const int r0   = blockIdx.x * 64;
    const int widx = blockIdx.y >> 3;          // 0=q 1=k 2=v
    const int c0   = (blockIdx.y & 7) * 64;
    const float* W = (widx == 0) ? Wq : (widx == 1 ? Wk : Wv);

    const int sr  = tid >> 3;
    const int scq = tid & 7;

    f32x4 acc[2][2] = {};

    for (int k0 = 0; k0 < 512; k0 += 32) {
        __syncthreads();
#pragma unroll
        for (int j = 0; j < 2; ++j) {
            const int r = sr + 32 * j;
            float4 av = *reinterpret_cast<const float4*>(x + (size_t)(r0 + r) * 512 + k0 + scq * 4);
            float4 bv = *reinterpret_cast<const float4*>(W + (size_t)(c0 + r) * 512 + k0 + scq * 4);
            bf16x4 ap = { (__bf16)av.x, (__bf16)av.y, (__bf16)av.z, (__bf16)av.w };
            bf16x4 bp = { (__bf16)bv.x, (__bf16)bv.y, (__bf16)bv.z, (__bf16)bv.w };
            *reinterpret_cast<bf16x4*>(&As[r][scq * 4]) = ap;
            *reinterpret_cast<bf16x4*>(&Bs[r][scq * 4]) = bp;
        }
        __syncthreads();
        bf16x8 af[2], bfr[2];
#pragma unroll
        for (int rt = 0; rt < 2; ++rt)
            af[rt] = *reinterpret_cast<const bf16x8*>(&As[wr * 32 + rt * 16 + l16][g * 8]);
#pragma unroll
        for (int ct = 0; ct < 2; ++ct)
            bfr[ct] = *reinterpret_cast<const bf16x8*>(&Bs[wc * 32 + ct * 16 + l16][g * 8]);
#pragma unroll
        for (int rt = 0; rt < 2; ++rt)
#pragma unroll
            for (int ct = 0; ct < 2; ++ct)
                acc[rt][ct] = MFMA16(af[rt], bfr[ct], acc[rt][ct]);
    }

    if (widx == 2) {
#pragma unroll
        for (int rt = 0; rt < 2; ++rt)
#pragma unroll
            for (int ct = 0; ct < 2; ++ct) {
                int r = r0 + wr * 32 + rt * 16 + 4 * g;
                int c = c0 + wc * 32 + ct * 16 + l16;
                int b = r >> 10, n = r & 1023, h = c >> 6, dh = c & 63;
                bf16x4 pv = { (__bf16)acc[rt][ct][0], (__bf16)acc[rt][ct][1],
                              (__bf16)acc[rt][ct][2], (__bf16)acc[rt][ct][3] };
                *reinterpret_cast<bf16x4*>(vto + (((size_t)b * 8 + h) * 64 + dh) * 1024 + n) = pv;
            }
    } else {
        __bf16* dst = (widx == 0) ? qo : ko;
        const float scale = (widx == 0) ? 0.125f : 1.0f;
#pragma unroll
        for (int rt = 0; rt < 2; ++rt)
#pragma unroll
            for (int ct = 0; ct < 2; ++ct)
#pragma unroll
                for (int reg = 0; reg < 4; ++reg) {
                    int r = r0 + wr * 32 + rt * 16 + 4 * g + reg;
                    int c = c0 + wc * 32 + ct * 16 + l16;
                    float val = acc[rt][ct][reg] * scale;
                    int b = r >> 10, n = r & 1023, h = c >> 6, dh = c & 63;
                    dst[(((size_t)b * 8 + h) * 1024 + n) * 64 + dh] = (__bf16)val;
                }
    }
}

// ---------------------------------------------------------------------------
// Kernel 2: bias re-tile (unchanged from R6; reads sequential, writes
// fragment-ordered bf16 biasT[b][nt][t][h][lane][8]).
// ---------------------------------------------------------------------------
__global__ __launch_bounds__(512) void bias_retile(
    const float* __restrict__ bias, __bf16* __restrict__ bT)
{
    __shared__ __bf16 st[16 * 2050];
    const int tid = threadIdx.x;
    const int bb  = blockIdx.x >> 6;
    const int nt  = blockIdx.x & 63;
    const int row = tid >> 5;
    const int col = tid & 31;
    const int h   = tid >> 6;
    const int l   = tid & 63;
    const int g   = l >> 4, l15 = l & 15;
    const float* src = bias + ((size_t)(bb * 1024 + nt * 16 + row)) * 8192;

    for (int mq = 0; mq < 4; ++mq) {
        __syncthreads();
#pragma unroll
        for (int q = 0; q < 16; ++q) {
            int f = (col + q * 32) * 4;
            f32x4 v = __builtin_nontemporal_load(
                reinterpret_cast<const f32x4*>(src + mq * 2048 + f));
            bf16x4 c = { (__bf16)v.x, (__bf16)v.y, (__bf16)v.z, (__bf16)v.w };
            *reinterpret_cast<bf16x4*>(&st[row * 2050 + f]) = c;
        }
        __syncthreads();
#pragma unroll
        for (int tl = 0; tl < 8; ++tl) {
            bf16x8 o;
#pragma unroll
            for (int k = 0; k < 8; ++k) {
                int r  = 4 * g + (k & 3);
                int ml = tl * 32 + ((k >> 2) << 4) + l15;
                o[k] = st[r * 2050 + ml * 8 + h];
            }
            size_t t = (size_t)mq * 8 + tl;
            *reinterpret_cast<bf16x8*>(
                bT + ((((size_t)bb * 64 + nt) * 32 + t) * 8 + h) * 512 + l * 8) = o;
        }
    }
}

// ---------------------------------------------------------------------------
// Kernel 3: split-m flash attention.  Grid (8 b, 64 nt, 4 ms): each block
// handles 8 m-tiles (256 K/V rows).  3 blocks/CU (24 waves) -> TLP covers
// whatever per-iteration latency remains.  Fixed-max softmax means partials
// combine by plain summation (no max rebase).  Partial o (f32) + l -> ws.
// ---------------------------------------------------------------------------
__global__ __launch_bounds__(512, 3) void attn_split(
    const __bf16* __restrict__ qw, const __bf16* __restrict__ kw,
    const __bf16* __restrict__ vtw, const __bf16* __restrict__ bT,
    float* __restrict__ wso, float* __restrict__ wsl)
{
    __shared__ __bf16 psm[8][16][40];
    const int tid  = threadIdx.x;
    const int w    = tid >> 6;
    const int lane = tid & 63;
    const int g    = lane >> 4, l16 = lane & 15;
    const int b    = blockIdx.x;
    const int nt   = blockIdx.y;
    const int ms   = blockIdx.z;
    const int n0   = nt * 16;
    const size_t bh = (size_t)b * 8 + w;

    bf16x8 qf[2];
#pragma unroll
    for (int kc = 0; kc < 2; ++kc)
        qf[kc] = *reinterpret_cast<const bf16x8*>(
            qw + (bh * 1024 + n0 + l16) * 64 + kc * 32 + g * 8);

    f32x4 o[4] = {};
    float lrun[4] = {0.f, 0.f, 0.f, 0.f};

    const __bf16* bslab = bT + (((size_t)(b * 64 + nt) * 32 * 8 + w) * 512) + lane * 8;

    // prologue for this split's first tile
    bf16x8 bc = *reinterpret_cast<const bf16x8*>(bslab + (size_t)(ms * 8) * 4096);
    bf16x8 kf[2][2];
#pragma unroll
    for (int ct = 0; ct < 2; ++ct)
#pragma unroll
        for (int kc = 0; kc < 2; ++kc)
            kf[ct][kc] = *reinterpret_cast<const bf16x8*>(
                kw + (bh * 1024 + ms * 256 + ct * 16 + l16) * 64 + kc * 32 + g * 8);

    for (int t = 0; t < 8; ++t) {
        const int m0 = ms * 256 + t * 32;

        // prefetch next tile's bias fragment + K; V loaded early for this tile
        bf16x8 bn = *reinterpret_cast<const bf16x8*>(
            bslab + (size_t)(ms * 8 + (t < 7 ? t + 1 : t)) * 4096);

        bf16x8 vf[4];
#pragma unroll
        for (int oc = 0; oc < 4; ++oc)
            vf[oc] = *reinterpret_cast<const bf16x8*>(
                vtw + (bh * 64 + oc * 16 + l16) * 1024 + m0 + g * 8);

        const int mn = (t < 7) ? m0 + 32 : m0;
        bf16x8 kn[2][2];
#pragma unroll
        for (int ct = 0; ct < 2; ++ct)
#pragma unroll
            for (int kc = 0; kc < 2; ++kc)
                kn[ct][kc] = *reinterpret_cast<const bf16x8*>(
                    kw + (bh * 1024 + mn + ct * 16 + l16) * 64 + kc * 32 + g * 8);

        f32x4 s[2] = {};
#pragma unroll
        for (int ct = 0; ct < 2; ++ct) {
            s[ct] = MFMA16(qf[0], kf[ct][0], s[ct]);
            s[ct] = MFMA16(qf[1], kf[ct][1], s[ct]);
        }

#pragma unroll
        for (int reg = 0; reg < 4; ++reg) {
            float p0 = __expf(s[0][reg] + (float)bc[reg]     - 16.0f);
            float p1 = __expf(s[1][reg] + (float)bc[4 + reg] - 16.0f);
            lrun[reg] += p0 + p1;
            psm[w][4 * g + reg][l16]      = (__bf16)p0;
            psm[w][4 * g + reg][16 + l16] = (__bf16)p1;
        }

        bf16x8 pf = *reinterpret_cast<const bf16x8*>(&psm[w][l16][g * 8]);
#pragma unroll
        for (int oc = 0; oc < 4; ++oc)
            o[oc] = MFMA16(pf, vf[oc], o[oc]);

        bc = bn;
#pragma unroll
        for (int ct = 0; ct < 2; ++ct)
#pragma unroll
            for (int kc = 0; kc < 2; ++kc)
                kf[ct][kc] = kn[ct][kc];
    }

    // reduce partial denominator across the 16 m-lanes (per n-row)
#pragma unroll
    for (int reg = 0; reg < 4; ++reg) {
        float l = lrun[reg];
        l += __shfl_xor(l, 1);
        l += __shfl_xor(l, 2);
        l += __shfl_xor(l, 4);
        l += __shfl_xor(l, 8);
        lrun[reg] = l;
    }

    // store partials: wso[ms][b][nt][tid][16], wsl[ms][b][nt][tid][4]
    {
        const size_t slot = ((size_t)(ms * 512 + b * 64 + nt)) * 512 + tid;
        float* po = wso + slot * 16;
#pragma unroll
        for (int oc = 0; oc < 4; ++oc)
            *reinterpret_cast<f32x4*>(po + oc * 4) = o[oc];
        *reinterpret_cast<f32x4*>(wsl + slot * 4) =
            f32x4{lrun[0], lrun[1], lrun[2], lrun[3]};
    }
}

// ---------------------------------------------------------------------------
// Kernel 4: combine 4 m-split partials, normalize, write bf16 O.
// Grid (8 b, 64 nt), 512 thr = (w, lane).
// ---------------------------------------------------------------------------
__global__ __launch_bounds__(512) void attn_reduce(
    const float* __restrict__ wso, const float* __restrict__ wsl,
    __bf16* __restrict__ ow)
{
    const int tid  = threadIdx.x;
    const int w    = tid >> 6;
    const int lane = tid & 63;
    const int g    = lane >> 4, l16 = lane & 15;
    const int b    = blockIdx.x;
    const int nt   = blockIdx.y;
    const int n0   = nt * 16;

    f32x4 o[4] = {};
    f32x4 l = {0.f, 0.f, 0.f, 0.f};
#pragma unroll
    for (int ms = 0; ms < 4; ++ms) {
        const size_t slot = ((size_t)(ms * 512 + b * 64 + nt)) * 512 + tid;
        const float* po = wso + slot * 16;
#pragma unroll
        for (int oc = 0; oc < 4; ++oc) {
            f32x4 v = *reinterpret_cast<const f32x4*>(po + oc * 4);
            o[oc].x += v.x; o[oc].y += v.y; o[oc].z += v.z; o[oc].w += v.w;
        }
        f32x4 lv = *reinterpret_cast<const f32x4*>(wsl + slot * 4);
        l.x += lv.x; l.y += lv.y; l.z += lv.z; l.w += lv.w;
    }
    float li[4] = {1.f / l.x, 1.f / l.y, 1.f / l.z, 1.f / l.w};
#pragma unroll
    for (int oc = 0; oc < 4; ++oc)
#pragma unroll
        for (int reg = 0; reg < 4; ++reg) {
            int n  = n0 + 4 * g + reg;
            int dh = oc * 16 + l16;
            ow[((size_t)b * 1024 + n) * 512 + w * 64 + dh] = (__bf16)(o[oc][reg] * li[reg]);
        }
}

// ---------------------------------------------------------------------------
// Kernel 5: output projection (unchanged).
// ---------------------------------------------------------------------------
__global__ __launch_bounds__(256) void gemm_out(
    const __bf16* __restrict__ a, const float* __restrict__ Wm,
    const float* __restrict__ bm, float* __restrict__ out)
{
    __shared__ __bf16 As[64][40];
    __shared__ __bf16 Bs[64][40];
    const int tid  = threadIdx.x;
    const int lane = tid & 63;
    const int wid  = tid >> 6;
    const int g    = lane >> 4, l16 = lane & 15;
    const int wr   = wid >> 1,  wc  = wid & 1;
    const int r0   = blockIdx.x * 64;
    const int c0   = blockIdx.y * 64;

    const int sra = tid >> 2, sca = tid & 3;
    const int srb = tid >> 3, scb = tid & 7;

    f32x4 acc[2][2] = {};
    for (int k0 = 0; k0 < 512; k0 += 32) {
        __syncthreads();
        {
            bf16x8 av = *reinterpret_cast<const bf16x8*>(a + (size_t)(r0 + sra) * 512 + k0 + sca * 8);
            *reinterpret_cast<bf16x8*>(&As[sra][sca * 8]) = av;
#pragma unroll
            for (int j = 0; j < 2; ++j) {
                int r = srb + 32 * j;
                float4 bv = *reinterpret_cast<const float4*>(Wm + (size_t)(c0 + r) * 512 + k0 + scb * 4);
                bf16x4 bp = { (__bf16)bv.x, (__bf16)bv.y, (__bf16)bv.z, (__bf16)bv.w };
                *reinterpret_cast<bf16x4*>(&Bs[r][scb * 4]) = bp;
            }
        }
        __syncthreads();
        bf16x8 af[2], bfr[2];
#pragma unroll
        for (int rt = 0; rt < 2; ++rt)
            af[rt] = *reinterpret_cast<const bf16x8*>(&As[wr * 32 + rt * 16 + l16][g * 8]);
#pragma unroll
        for (int ct = 0; ct < 2; ++ct)
            bfr[ct] = *reinterpret_cast<const bf16x8*>(&Bs[wc * 32 + ct * 16 + l16][g * 8]);
#pragma unroll
        for (int rt = 0; rt < 2; ++rt)
#pragma unroll
            for (int ct = 0; ct < 2; ++ct)
                acc[rt][ct] = MFMA16(af[rt], bfr[ct], acc[rt][ct]);
    }

#pragma unroll
    for (int rt = 0; rt < 2; ++rt)
#pragma unroll
        for (int ct = 0; ct < 2; ++ct)
#pragma unroll
            for (int reg = 0; reg < 4; ++reg) {
                int r = r0 + wr * 32 + rt * 16 + 4 * g + reg;
                int c = c0 + wc * 32 + ct * 16 + l16;
                out[(size_t)r * 512 + c] = acc[rt][ct][reg] + bm[c];
            }
}

// ---------------------------------------------------------------------------
extern "C" void kernel_launch(void* const* d_in, const int* in_sizes, int n_in,
                              void* d_out, int out_size, void* d_ws, size_t ws_size,
                              hipStream_t stream)
{
    const float* x    = (const float*)d_in[0];
    const float* bias = (const float*)d_in[1];
    const float* Wq   = (const float*)d_in[2];
    const float* Wk   = (const float*)d_in[3];
    const float* Wv   = (const float*)d_in[4];
    const float* Wm   = (const float*)d_in[5];
    const float* bm   = (const float*)d_in[6];
    float* out = (float*)d_out;

    const size_t SEG = (size_t)8 * 8 * 1024 * 64;   // 4M elems (8 MB bf16) each
    __bf16* qw  = (__bf16*)d_ws;
    __bf16* kw  = qw + SEG;
    __bf16* vtw = kw + SEG;
    __bf16* ow  = vtw + SEG;
    __bf16* bT  = (__bf16*)((char*)d_ws + ((size_t)64 << 20));   // 128 MB
    float*  wso = (float*)((char*)d_ws + ((size_t)192 << 20));   // 64 MB
    float*  wsl = (float*)((char*)d_ws + ((size_t)264 << 20));   // 16 MB

    bias_retile<<<dim3(512), 512, 0, stream>>>(bias, bT);
    gemm_qkv   <<<dim3(128, 24), 256, 0, stream>>>(x, Wq, Wk, Wv, qw, kw, vtw);
    attn_split <<<dim3(8, 64, 4), 512, 0, stream>>>(qw, kw, vtw, bT, wso, wsl);
    attn_reduce<<<dim3(8, 64), 512, 0, stream>>>(wso, wsl, ow);
    gemm_out   <<<dim3(128, 8), 256, 0, stream>>>(ow, Wm, bm, out);
}

// Round 8
// 178.860 us; speedup vs baseline: 1.6939x; 1.6939x over previous
//
#include <hip/hip_runtime.h>
#include <hip/hip_bf16.h>

typedef __bf16 bf16x8 __attribute__((ext_vector_type(8)));
typedef __bf16 bf16x4 __attribute__((ext_vector_type(4)));
typedef float  f32x4  __attribute__((ext_vector_type(4)));

#define MFMA16(a, b, c) __builtin_amdgcn_mfma_f32_16x16x32_bf16((a), (b), (c), 0, 0, 0)

// Problem constants: B=8, N=1024, D=512, H=8, DH=64

// ---------------------------------------------------------------------------
// Kernel 1: fused QKV projection (unchanged).
// ---------------------------------------------------------------------------
__global__ __launch_bounds__(256) void gemm_qkv(
    const float* __restrict__ x,
    const float* __restrict__ Wq, const float* __restrict__ Wk,
    const float* __restrict__ Wv,
    __bf16* __restrict__ qo, __bf16* __restrict__ ko, __bf16* __restrict__ vto)
{
    __shared__ __bf16 As[64][40];
    __shared__ __bf16 Bs[64][40];
    const int tid  = threadIdx.x;
    const int lane = tid & 63;
    const int wid  = tid >> 6;
    const int g    = lane >> 4, l16 = lane & 15;
    const int wr   = wid >> 1,  wc  = wid & 1;
    const int r0   = blockIdx.x * 64;
    const int widx = blockIdx.y >> 3;          // 0=q 1=k 2=v
    const int c0   = (blockIdx.y & 7) * 64;
    const float* W = (widx == 0) ? Wq : (widx == 1 ? Wk : Wv);

    const int sr  = tid >> 3;
    const int scq = tid & 7;

    f32x4 acc[2][2] = {};

    for (int k0 = 0; k0 < 512; k0 += 32) {
        __syncthreads();
#pragma unroll
        for (int j = 0; j < 2; ++j) {
            const int r = sr + 32 * j;
            float4 av = *reinterpret_cast<const float4*>(x + (size_t)(r0 + r) * 512 + k0 + scq * 4);
            float4 bv = *reinterpret_cast<const float4*>(W + (size_t)(c0 + r) * 512 + k0 + scq * 4);
            bf16x4 ap = { (__bf16)av.x, (__bf16)av.y, (__bf16)av.z, (__bf16)av.w };
            bf16x4 bp = { (__bf16)bv.x, (__bf16)bv.y, (__bf16)bv.z, (__bf16)bv.w };
            *reinterpret_cast<bf16x4*>(&As[r][scq * 4]) = ap;
            *reinterpret_cast<bf16x4*>(&Bs[r][scq * 4]) = bp;
        }
        __syncthreads();
        bf16x8 af[2], bfr[2];
#pragma unroll
        for (int rt = 0; rt < 2; ++rt)
            af[rt] = *reinterpret_cast<const bf16x8*>(&As[wr * 32 + rt * 16 + l16][g * 8]);
#pragma unroll
        for (int ct = 0; ct < 2; ++ct)
            bfr[ct] = *reinterpret_cast<const bf16x8*>(&Bs[wc * 32 + ct * 16 + l16][g * 8]);
#pragma unroll
        for (int rt = 0; rt < 2; ++rt)
#pragma unroll
            for (int ct = 0; ct < 2; ++ct)
                acc[rt][ct] = MFMA16(af[rt], bfr[ct], acc[rt][ct]);
    }

    if (widx == 2) {
#pragma unroll
        for (int rt = 0; rt < 2; ++rt)
#pragma unroll
            for (int ct = 0; ct < 2; ++ct) {
                int r = r0 + wr * 32 + rt * 16 + 4 * g;
                int c = c0 + wc * 32 + ct * 16 + l16;
                int b = r >> 10, n = r & 1023, h = c >> 6, dh = c & 63;
                bf16x4 pv = { (__bf16)acc[rt][ct][0], (__bf16)acc[rt][ct][1],
                              (__bf16)acc[rt][ct][2], (__bf16)acc[rt][ct][3] };
                *reinterpret_cast<bf16x4*>(vto + (((size_t)b * 8 + h) * 64 + dh) * 1024 + n) = pv;
            }
    } else {
        __bf16* dst = (widx == 0) ? qo : ko;
        const float scale = (widx == 0) ? 0.125f : 1.0f;
#pragma unroll
        for (int rt = 0; rt < 2; ++rt)
#pragma unroll
            for (int ct = 0; ct < 2; ++ct)
#pragma unroll
                for (int reg = 0; reg < 4; ++reg) {
                    int r = r0 + wr * 32 + rt * 16 + 4 * g + reg;
                    int c = c0 + wc * 32 + ct * 16 + l16;
                    float val = acc[rt][ct][reg] * scale;
                    int b = r >> 10, n = r & 1023, h = c >> 6, dh = c & 63;
                    dst[(((size_t)b * 8 + h) * 1024 + n) * 64 + dh] = (__bf16)val;
                }
    }
}

// ---------------------------------------------------------------------------
// Kernel 2: bias re-tile (unchanged): bias[b][n][m][h] f32 -> bf16
// biasT[b][nt16][t][h][lane][8] in per-lane MFMA fragment order.
// ---------------------------------------------------------------------------
__global__ __launch_bounds__(512) void bias_retile(
    const float* __restrict__ bias, __bf16* __restrict__ bT)
{
    __shared__ __bf16 st[16 * 2050];
    const int tid = threadIdx.x;
    const int bb  = blockIdx.x >> 6;
    const int nt  = blockIdx.x & 63;
    const int row = tid >> 5;
    const int col = tid & 31;
    const int h   = tid >> 6;
    const int l   = tid & 63;
    const int g   = l >> 4, l15 = l & 15;
    const float* src = bias + ((size_t)(bb * 1024 + nt * 16 + row)) * 8192;

    for (int mq = 0; mq < 4; ++mq) {
        __syncthreads();
#pragma unroll
        for (int q = 0; q < 16; ++q) {
            int f = (col + q * 32) * 4;
            f32x4 v = __builtin_nontemporal_load(
                reinterpret_cast<const f32x4*>(src + mq * 2048 + f));
            bf16x4 c = { (__bf16)v.x, (__bf16)v.y, (__bf16)v.z, (__bf16)v.w };
            *reinterpret_cast<bf16x4*>(&st[row * 2050 + f]) = c;
        }
        __syncthreads();
#pragma unroll
        for (int tl = 0; tl < 8; ++tl) {
            bf16x8 o;
#pragma unroll
            for (int k = 0; k < 8; ++k) {
                int r  = 4 * g + (k & 3);
                int ml = tl * 32 + ((k >> 2) << 4) + l15;
                o[k] = st[r * 2050 + ml * 8 + h];
            }
            size_t t = (size_t)mq * 8 + tl;
            *reinterpret_cast<bf16x8*>(
                bT + ((((size_t)bb * 64 + nt) * 32 + t) * 8 + h) * 512 + l * 8) = o;
        }
    }
}

// ---------------------------------------------------------------------------
// Kernel 3: flash attention, one (b,h) per block, 128 Q-rows (8 waves x 16).
// K/V staged in LDS with COALESCED global reads (this was the wall: direct
// fragment loads were 16-line gathers); fragments via padded ds_read_b128.
// Double-buffered, one barrier/iter.  Bias from pre-tiled bT: one bf16x8
// register load per wave per tile.  Fixed-max softmax.
// Grid x=bh (64) -> each XCD's L2 holds 8 heads' K/V (4MB); y=nt (8) reuses.
// ---------------------------------------------------------------------------
__global__ __launch_bounds__(512, 4) void attn_v3(
    const __bf16* __restrict__ qw, const __bf16* __restrict__ kw,
    const __bf16* __restrict__ vtw, const __bf16* __restrict__ bT,
    __bf16* __restrict__ ow)
{
    __shared__ __bf16 Ks[2][32][72];   // [m][dh], stride 72 (pad 8)
    __shared__ __bf16 Vs[2][64][40];   // [dh][m], stride 40 (pad 8)
    __shared__ __bf16 psm[8][16][40];  // per-wave P bounce
    const int tid  = threadIdx.x;
    const int w    = tid >> 6;
    const int lane = tid & 63;
    const int g    = lane >> 4, l16 = lane & 15;
    const int bh   = blockIdx.x;            // b*8+h
    const int b    = bh >> 3, h = bh & 7;
    const int nt8  = blockIdx.y;             // 128-row tile
    const int n0   = nt8 * 128 + w * 16;     // this wave's 16 Q rows
    const int nt16 = nt8 * 8 + w;            // global 16-row tile index
    const size_t bhs = (size_t)bh;

    // staging assignments
    const int krow = tid >> 4, kc4 = (tid & 15) * 4;   // K: 32 rows x 16 chunks
    const int vrow = tid >> 3, vc4 = (tid & 7) * 4;    // V: 64 rows x 8 chunks

    // Q fragments, resident
    bf16x8 qf[2];
#pragma unroll
    for (int kc = 0; kc < 2; ++kc)
        qf[kc] = *reinterpret_cast<const bf16x8*>(
            qw + (bhs * 1024 + n0 + l16) * 64 + kc * 32 + g * 8);

    f32x4 o[4] = {};
    float lrun[4] = {0.f, 0.f, 0.f, 0.f};

    // bias slab: bT[((b*64+nt16)*32 + t)*8 + h][lane*8], t-stride 4096
    const __bf16* bslab = bT + (((size_t)(b * 64 + nt16) * 32 * 8) + h) * 512 + lane * 8;
    bf16x8 bc = *reinterpret_cast<const bf16x8*>(bslab);

    // prologue: stage tile 0 into buf 0
    {
        bf16x4 kr = *reinterpret_cast<const bf16x4*>(kw + (bhs * 1024 + krow) * 64 + kc4);
        bf16x4 vr = *reinterpret_cast<const bf16x4*>(vtw + (bhs * 64 + vrow) * 1024 + vc4);
        *reinterpret_cast<bf16x4*>(&Ks[0][krow][kc4]) = kr;
        *reinterpret_cast<bf16x4*>(&Vs[0][vrow][vc4]) = vr;
    }
    __syncthreads();

    for (int t = 0; t < 32; ++t) {
        const int cur = t & 1;
        const int mn  = (t < 31) ? (t + 1) * 32 : t * 32;

        // issue next tile's global loads (coalesced rows)
        bf16x4 kr = *reinterpret_cast<const bf16x4*>(kw + (bhs * 1024 + mn + krow) * 64 + kc4);
        bf16x4 vr = *reinterpret_cast<const bf16x4*>(vtw + (bhs * 64 + vrow) * 1024 + mn + vc4);
        bf16x8 bn = *reinterpret_cast<const bf16x8*>(
            bslab + (size_t)(t < 31 ? t + 1 : t) * 4096);

        // fragments from LDS (padded strides -> ~2-way conflicts, free)
        bf16x8 kf[2][2], vf[4];
#pragma unroll
        for (int ct = 0; ct < 2; ++ct)
#pragma unroll
            for (int kc = 0; kc < 2; ++kc)
                kf[ct][kc] = *reinterpret_cast<const bf16x8*>(&Ks[cur][ct * 16 + l16][kc * 32 + g * 8]);
#pragma unroll
        for (int oc = 0; oc < 4; ++oc)
            vf[oc] = *reinterpret_cast<const bf16x8*>(&Vs[cur][oc * 16 + l16][g * 8]);

        // QK^T
        f32x4 s[2] = {};
#pragma unroll
        for (int ct = 0; ct < 2; ++ct) {
            s[ct] = MFMA16(qf[0], kf[ct][0], s[ct]);
            s[ct] = MFMA16(qf[1], kf[ct][1], s[ct]);
        }

        // fixed-max softmax with register-resident bias
#pragma unroll
        for (int reg = 0; reg < 4; ++reg) {
            float p0 = __expf(s[0][reg] + (float)bc[reg]     - 16.0f);
            float p1 = __expf(s[1][reg] + (float)bc[4 + reg] - 16.0f);
            lrun[reg] += p0 + p1;
            psm[w][4 * g + reg][l16]      = (__bf16)p0;
            psm[w][4 * g + reg][16 + l16] = (__bf16)p1;
        }

        // wave-local P relayout + PV
        bf16x8 pf = *reinterpret_cast<const bf16x8*>(&psm[w][l16][g * 8]);
#pragma unroll
        for (int oc = 0; oc < 4; ++oc)
            o[oc] = MFMA16(pf, vf[oc], o[oc]);

        // write next tile to the other buffer, then barrier
        *reinterpret_cast<bf16x4*>(&Ks[cur ^ 1][krow][kc4]) = kr;
        *reinterpret_cast<bf16x4*>(&Vs[cur ^ 1][vrow][vc4]) = vr;
        bc = bn;
        __syncthreads();
    }

    // epilogue: reduce denominator across the 16 m-lanes
#pragma unroll
    for (int reg = 0; reg < 4; ++reg) {
        float l = lrun[reg];
        l += __shfl_xor(l, 1);
        l += __shfl_xor(l, 2);
        l += __shfl_xor(l, 4);
        l += __shfl_xor(l, 8);
        lrun[reg] = l;
    }

#pragma unroll
    for (int oc = 0; oc < 4; ++oc)
#pragma unroll
        for (int reg = 0; reg < 4; ++reg) {
            int n  = n0 + 4 * g + reg;
            int dh = oc * 16 + l16;
            float val = o[oc][reg] / lrun[reg];
            ow[((size_t)b * 1024 + n) * 512 + h * 64 + dh] = (__bf16)val;
        }
}

// ---------------------------------------------------------------------------
// Kernel 4: output projection (unchanged).
// ---------------------------------------------------------------------------
__global__ __launch_bounds__(256) void gemm_out(
    const __bf16* __restrict__ a, const float* __restrict__ Wm,
    const float* __restrict__ bm, float* __restrict__ out)
{
    __shared__ __bf16 As[64][40];
    __shared__ __bf16 Bs[64][40];
    const int tid  = threadIdx.x;
    const int lane = tid & 63;
    const int wid  = tid >> 6;
    const int g    = lane >> 4, l16 = lane & 15;
    const int wr   = wid >> 1,  wc  = wid & 1;
    const int r0   = blockIdx.x * 64;
    const int c0   = blockIdx.y * 64;

    const int sra = tid >> 2, sca = tid & 3;
    const int srb = tid >> 3, scb = tid & 7;

    f32x4 acc[2][2] = {};
    for (int k0 = 0; k0 < 512; k0 += 32) {
        __syncthreads();
        {
            bf16x8 av = *reinterpret_cast<const bf16x8*>(a + (size_t)(r0 + sra) * 512 + k0 + sca * 8);
            *reinterpret_cast<bf16x8*>(&As[sra][sca * 8]) = av;
#pragma unroll
            for (int j = 0; j < 2; ++j) {
                int r = srb + 32 * j;
                float4 bv = *reinterpret_cast<const float4*>(Wm + (size_t)(c0 + r) * 512 + k0 + scb * 4);
                bf16x4 bp = { (__bf16)bv.x, (__bf16)bv.y, (__bf16)bv.z, (__bf16)bv.w };
                *reinterpret_cast<bf16x4*>(&Bs[r][scb * 4]) = bp;
            }
        }
        __syncthreads();
        bf16x8 af[2], bfr[2];
#pragma unroll
        for (int rt = 0; rt < 2; ++rt)
            af[rt] = *reinterpret_cast<const bf16x8*>(&As[wr * 32 + rt * 16 + l16][g * 8]);
#pragma unroll
        for (int ct = 0; ct < 2; ++ct)
            bfr[ct] = *reinterpret_cast<const bf16x8*>(&Bs[wc * 32 + ct * 16 + l16][g * 8]);
#pragma unroll
        for (int rt = 0; rt < 2; ++rt)
#pragma unroll
            for (int ct = 0; ct < 2; ++ct)
                acc[rt][ct] = MFMA16(af[rt], bfr[ct], acc[rt][ct]);
    }

#pragma unroll
    for (int rt = 0; rt < 2; ++rt)
#pragma unroll
        for (int ct = 0; ct < 2; ++ct)
#pragma unroll
            for (int reg = 0; reg < 4; ++reg) {
                int r = r0 + wr * 32 + rt * 16 + 4 * g + reg;
                int c = c0 + wc * 32 + ct * 16 + l16;
                out[(size_t)r * 512 + c] = acc[rt][ct][reg] + bm[c];
            }
}

// ---------------------------------------------------------------------------
extern "C" void kernel_launch(void* const* d_in, const int* in_sizes, int n_in,
                              void* d_out, int out_size, void* d_ws, size_t ws_size,
                              hipStream_t stream)
{
    const float* x    = (const float*)d_in[0];
    const float* bias = (const float*)d_in[1];
    const float* Wq   = (const float*)d_in[2];
    const float* Wk   = (const float*)d_in[3];
    const float* Wv   = (const float*)d_in[4];
    const float* Wm   = (const float*)d_in[5];
    const float* bm   = (const float*)d_in[6];
    float* out = (float*)d_out;

    const size_t SEG = (size_t)8 * 8 * 1024 * 64;   // 4M elems (8 MB bf16) each
    __bf16* qw  = (__bf16*)d_ws;
    __bf16* kw  = qw + SEG;
    __bf16* vtw = kw + SEG;
    __bf16* ow  = vtw + SEG;
    __bf16* bT  = (__bf16*)((char*)d_ws + ((size_t)64 << 20));   // 128 MB

    bias_retile<<<dim3(512), 512, 0, stream>>>(bias, bT);
    gemm_qkv   <<<dim3(128, 24), 256, 0, stream>>>(x, Wq, Wk, Wv, qw, kw, vtw);
    attn_v3    <<<dim3(64, 8), 512, 0, stream>>>(qw, kw, vtw, bT, ow);
    gemm_out   <<<dim3(128, 8), 256, 0, stream>>>(ow, Wm, bm, out);
}

// Round 9
// 178.452 us; speedup vs baseline: 1.6977x; 1.0023x over previous
//
#include <hip/hip_runtime.h>
#include <hip/hip_bf16.h>

typedef __bf16 bf16x8 __attribute__((ext_vector_type(8)));
typedef __bf16 bf16x4 __attribute__((ext_vector_type(4)));
typedef float  f32x4  __attribute__((ext_vector_type(4)));

#define MFMA16(a, b, c) __builtin_amdgcn_mfma_f32_16x16x32_bf16((a), (b), (c), 0, 0, 0)

// LDS-visibility barrier that does NOT drain outstanding global loads
// (__syncthreads emits s_waitcnt vmcnt(0) and kills cross-iteration prefetch).
// sched_barrier(0) per guide rule #18 (compiler may hoist past inline-asm wait).
__device__ __forceinline__ void barrier_lds_only() {
    asm volatile("s_waitcnt lgkmcnt(0)" ::: "memory");
    __builtin_amdgcn_s_barrier();
    __builtin_amdgcn_sched_barrier(0);
}

// Problem constants: B=8, N=1024, D=512, H=8, DH=64

// ---------------------------------------------------------------------------
// Kernel 1: fused QKV projection (unchanged).
// ---------------------------------------------------------------------------
__global__ __launch_bounds__(256) void gemm_qkv(
    const float* __restrict__ x,
    const float* __restrict__ Wq, const float* __restrict__ Wk,
    const float* __restrict__ Wv,
    __bf16* __restrict__ qo, __bf16* __restrict__ ko, __bf16* __restrict__ vto)
{
    __shared__ __bf16 As[64][40];
    __shared__ __bf16 Bs[64][40];
    const int tid  = threadIdx.x;
    const int lane = tid & 63;
    const int wid  = tid >> 6;
    const int g    = lane >> 4, l16 = lane & 15;
    const int wr   = wid >> 1,  wc  = wid & 1;
    const int r0   = blockIdx.x * 64;
    const int widx = blockIdx.y >> 3;          // 0=q 1=k 2=v
    const int c0   = (blockIdx.y & 7) * 64;
    const float* W = (widx == 0) ? Wq : (widx == 1 ? Wk : Wv);

    const int sr  = tid >> 3;
    const int scq = tid & 7;

    f32x4 acc[2][2] = {};

    for (int k0 = 0; k0 < 512; k0 += 32) {
        __syncthreads();
#pragma unroll
        for (int j = 0; j < 2; ++j) {
            const int r = sr + 32 * j;
            float4 av = *reinterpret_cast<const float4*>(x + (size_t)(r0 + r) * 512 + k0 + scq * 4);
            float4 bv = *reinterpret_cast<const float4*>(W + (size_t)(c0 + r) * 512 + k0 + scq * 4);
            bf16x4 ap = { (__bf16)av.x, (__bf16)av.y, (__bf16)av.z, (__bf16)av.w };
            bf16x4 bp = { (__bf16)bv.x, (__bf16)bv.y, (__bf16)bv.z, (__bf16)bv.w };
            *reinterpret_cast<bf16x4*>(&As[r][scq * 4]) = ap;
            *reinterpret_cast<bf16x4*>(&Bs[r][scq * 4]) = bp;
        }
        __syncthreads();
        bf16x8 af[2], bfr[2];
#pragma unroll
        for (int rt = 0; rt < 2; ++rt)
            af[rt] = *reinterpret_cast<const bf16x8*>(&As[wr * 32 + rt * 16 + l16][g * 8]);
#pragma unroll
        for (int ct = 0; ct < 2; ++ct)
            bfr[ct] = *reinterpret_cast<const bf16x8*>(&Bs[wc * 32 + ct * 16 + l16][g * 8]);
#pragma unroll
        for (int rt = 0; rt < 2; ++rt)
#pragma unroll
            for (int ct = 0; ct < 2; ++ct)
                acc[rt][ct] = MFMA16(af[rt], bfr[ct], acc[rt][ct]);
    }

    if (widx == 2) {
#pragma unroll
        for (int rt = 0; rt < 2; ++rt)
#pragma unroll
            for (int ct = 0; ct < 2; ++ct) {
                int r = r0 + wr * 32 + rt * 16 + 4 * g;
                int c = c0 + wc * 32 + ct * 16 + l16;
                int b = r >> 10, n = r & 1023, h = c >> 6, dh = c & 63;
                bf16x4 pv = { (__bf16)acc[rt][ct][0], (__bf16)acc[rt][ct][1],
                              (__bf16)acc[rt][ct][2], (__bf16)acc[rt][ct][3] };
                *reinterpret_cast<bf16x4*>(vto + (((size_t)b * 8 + h) * 64 + dh) * 1024 + n) = pv;
            }
    } else {
        __bf16* dst = (widx == 0) ? qo : ko;
        const float scale = (widx == 0) ? 0.125f : 1.0f;
#pragma unroll
        for (int rt = 0; rt < 2; ++rt)
#pragma unroll
            for (int ct = 0; ct < 2; ++ct)
#pragma unroll
                for (int reg = 0; reg < 4; ++reg) {
                    int r = r0 + wr * 32 + rt * 16 + 4 * g + reg;
                    int c = c0 + wc * 32 + ct * 16 + l16;
                    float val = acc[rt][ct][reg] * scale;
                    int b = r >> 10, n = r & 1023, h = c >> 6, dh = c & 63;
                    dst[(((size_t)b * 8 + h) * 1024 + n) * 64 + dh] = (__bf16)val;
                }
    }
}

// ---------------------------------------------------------------------------
// Kernel 2: bias re-tile (unchanged): bias[b][n][m][h] f32 -> bf16
// biasT[b][nt16][t][h][lane][8] in per-lane MFMA fragment order.
// ---------------------------------------------------------------------------
__global__ __launch_bounds__(512) void bias_retile(
    const float* __restrict__ bias, __bf16* __restrict__ bT)
{
    __shared__ __bf16 st[16 * 2050];
    const int tid = threadIdx.x;
    const int bb  = blockIdx.x >> 6;
    const int nt  = blockIdx.x & 63;
    const int row = tid >> 5;
    const int col = tid & 31;
    const int h   = tid >> 6;
    const int l   = tid & 63;
    const int g   = l >> 4, l15 = l & 15;
    const float* src = bias + ((size_t)(bb * 1024 + nt * 16 + row)) * 8192;

    for (int mq = 0; mq < 4; ++mq) {
        __syncthreads();
#pragma unroll
        for (int q = 0; q < 16; ++q) {
            int f = (col + q * 32) * 4;
            f32x4 v = __builtin_nontemporal_load(
                reinterpret_cast<const f32x4*>(src + mq * 2048 + f));
            bf16x4 c = { (__bf16)v.x, (__bf16)v.y, (__bf16)v.z, (__bf16)v.w };
            *reinterpret_cast<bf16x4*>(&st[row * 2050 + f]) = c;
        }
        __syncthreads();
#pragma unroll
        for (int tl = 0; tl < 8; ++tl) {
            bf16x8 o;
#pragma unroll
            for (int k = 0; k < 8; ++k) {
                int r  = 4 * g + (k & 3);
                int ml = tl * 32 + ((k >> 2) << 4) + l15;
                o[k] = st[r * 2050 + ml * 8 + h];
            }
            size_t t = (size_t)mq * 8 + tl;
            *reinterpret_cast<bf16x8*>(
                bT + ((((size_t)bb * 64 + nt) * 32 + t) * 8 + h) * 512 + l * 8) = o;
        }
    }
}

// ---------------------------------------------------------------------------
// Kernel 3: flash attention, one (b,h) per block, 128 Q-rows (8 waves x 16).
// K/V LDS-staged with coalesced reads (R8's confirmed fix), double-buffered.
// NEW (R9): lgkm-only barrier (global loads stay in flight across iters,
// counted vmcnt) + 2-DEEP register prefetch pipeline (pendA/pendB, manual
// 2x unroll for static indexing) -> ~2 iterations of latency cover.
// ---------------------------------------------------------------------------
__global__ __launch_bounds__(512, 4) void attn_v3(
    const __bf16* __restrict__ qw, const __bf16* __restrict__ kw,
    const __bf16* __restrict__ vtw, const __bf16* __restrict__ bT,
    __bf16* __restrict__ ow)
{
    __shared__ __bf16 Ks[2][32][72];   // [m][dh], stride 72 (2-way = free)
    __shared__ __bf16 Vs[2][64][40];   // [dh][m], stride 40 (2-way = free)
    __shared__ __bf16 psm[8][16][40];  // per-wave P bounce
    const int tid  = threadIdx.x;
    const int w    = tid >> 6;
    const int lane = tid & 63;
    const int g    = lane >> 4, l16 = lane & 15;
    const int bh   = blockIdx.x;            // b*8+h
    const int b    = bh >> 3, h = bh & 7;
    const int nt8  = blockIdx.y;
    const int n0   = nt8 * 128 + w * 16;
    const int nt16 = nt8 * 8 + w;
    const size_t bhs = (size_t)bh;

    const int krow = tid >> 4, kc4 = (tid & 15) * 4;   // K: 32 rows x 16 chunks
    const int vrow = tid >> 3, vc4 = (tid & 7) * 4;    // V: 64 rows x 8 chunks

    bf16x8 qf[2];
#pragma unroll
    for (int kc = 0; kc < 2; ++kc)
        qf[kc] = *reinterpret_cast<const bf16x8*>(
            qw + (bhs * 1024 + n0 + l16) * 64 + kc * 32 + g * 8);

    f32x4 o[4] = {};
    float lrun[4] = {0.f, 0.f, 0.f, 0.f};

    const __bf16* bslab = bT + (((size_t)(b * 64 + nt16) * 32 * 8) + h) * 512 + lane * 8;
    const __bf16* kbase = kw + bhs * 1024 * 64;
    const __bf16* vbase = vtw + bhs * 64 * 1024;

    // ---- prologue ----
    // bias tile 0 -> bc
    bf16x8 bc = *reinterpret_cast<const bf16x8*>(bslab);
    // stage tile 0 -> buf0
    {
        bf16x4 kr = *reinterpret_cast<const bf16x4*>(kbase + (size_t)krow * 64 + kc4);
        bf16x4 vr = *reinterpret_cast<const bf16x4*>(vbase + (size_t)vrow * 1024 + vc4);
        *reinterpret_cast<bf16x4*>(&Ks[0][krow][kc4]) = kr;
        *reinterpret_cast<bf16x4*>(&Vs[0][vrow][vc4]) = vr;
    }
    // pendA = tile 1, pendB = tile 2
    bf16x4 kA = *reinterpret_cast<const bf16x4*>(kbase + (size_t)(32 + krow) * 64 + kc4);
    bf16x4 vA = *reinterpret_cast<const bf16x4*>(vbase + (size_t)vrow * 1024 + 32 + vc4);
    bf16x8 bA = *reinterpret_cast<const bf16x8*>(bslab + (size_t)1 * 4096);
    bf16x4 kB = *reinterpret_cast<const bf16x4*>(kbase + (size_t)(64 + krow) * 64 + kc4);
    bf16x4 vB = *reinterpret_cast<const bf16x4*>(vbase + (size_t)vrow * 1024 + 64 + vc4);
    bf16x8 bB = *reinterpret_cast<const bf16x8*>(bslab + (size_t)2 * 4096);

    __syncthreads();   // tile 0 staged (full barrier once is fine)

    // one m-tile step; CUR = buffer holding tile t, pend regs of this phase
#define ATTN_STEP(t, CUR, KP, VP, BP)                                          \
    {                                                                          \
        bf16x8 kf[2][2], vf[4];                                                \
        _Pragma("unroll")                                                      \
        for (int ct = 0; ct < 2; ++ct)                                         \
            _Pragma("unroll")                                                  \
            for (int kc = 0; kc < 2; ++kc)                                     \
                kf[ct][kc] = *reinterpret_cast<const bf16x8*>(                 \
                    &Ks[CUR][ct * 16 + l16][kc * 32 + g * 8]);                 \
        _Pragma("unroll")                                                      \
        for (int oc = 0; oc < 4; ++oc)                                         \
            vf[oc] = *reinterpret_cast<const bf16x8*>(&Vs[CUR][oc * 16 + l16][g * 8]); \
        f32x4 s[2] = {};                                                       \
        _Pragma("unroll")                                                      \
        for (int ct = 0; ct < 2; ++ct) {                                       \
            s[ct] = MFMA16(qf[0], kf[ct][0], s[ct]);                           \
            s[ct] = MFMA16(qf[1], kf[ct][1], s[ct]);                           \
        }                                                                      \
        _Pragma("unroll")                                                      \
        for (int reg = 0; reg < 4; ++reg) {                                    \
            float p0 = __expf(s[0][reg] + (float)bc[reg]     - 16.0f);         \
            float p1 = __expf(s[1][reg] + (float)bc[4 + reg] - 16.0f);         \
            lrun[reg] += p0 + p1;                                              \
            psm[w][4 * g + reg][l16]      = (__bf16)p0;                        \
            psm[w][4 * g + reg][16 + l16] = (__bf16)p1;                        \
        }                                                                      \
        bf16x8 pf = *reinterpret_cast<const bf16x8*>(&psm[w][l16][g * 8]);     \
        _Pragma("unroll")                                                      \
        for (int oc = 0; oc < 4; ++oc)                                         \
            o[oc] = MFMA16(pf, vf[oc], o[oc]);                                 \
        /* write tile t+1 (pend, issued 2 iters ago -> counted vmcnt) */       \
        *reinterpret_cast<bf16x4*>(&Ks[(CUR) ^ 1][krow][kc4]) = KP;            \
        *reinterpret_cast<bf16x4*>(&Vs[(CUR) ^ 1][vrow][vc4]) = VP;            \
        bc = BP;                                                               \
        /* issue loads for tile t+3 into the same pend regs */                 \
        {                                                                      \
            const int tn = ((t) + 3 < 32) ? (t) + 3 : 31;                      \
            const int mo = tn * 32;                                            \
            KP = *reinterpret_cast<const bf16x4*>(kbase + (size_t)(mo + krow) * 64 + kc4);      \
            VP = *reinterpret_cast<const bf16x4*>(vbase + (size_t)vrow * 1024 + mo + vc4);      \
            BP = *reinterpret_cast<const bf16x8*>(bslab + (size_t)tn * 4096);  \
        }                                                                      \
        barrier_lds_only();                                                    \
    }

    for (int t = 0; t < 32; t += 2) {
        ATTN_STEP(t,     0, kA, vA, bA)
        ATTN_STEP(t + 1, 1, kB, vB, bB)
    }
#undef ATTN_STEP

    // epilogue: reduce denominator across the 16 m-lanes
#pragma unroll
    for (int reg = 0; reg < 4; ++reg) {
        float l = lrun[reg];
        l += __shfl_xor(l, 1);
        l += __shfl_xor(l, 2);
        l += __shfl_xor(l, 4);
        l += __shfl_xor(l, 8);
        lrun[reg] = l;
    }

#pragma unroll
    for (int oc = 0; oc < 4; ++oc)
#pragma unroll
        for (int reg = 0; reg < 4; ++reg) {
            int n  = n0 + 4 * g + reg;
            int dh = oc * 16 + l16;
            float val = o[oc][reg] / lrun[reg];
            ow[((size_t)b * 1024 + n) * 512 + h * 64 + dh] = (__bf16)val;
        }
}

// ---------------------------------------------------------------------------
// Kernel 4: output projection (unchanged).
// ---------------------------------------------------------------------------
__global__ __launch_bounds__(256) void gemm_out(
    const __bf16* __restrict__ a, const float* __restrict__ Wm,
    const float* __restrict__ bm, float* __restrict__ out)
{
    __shared__ __bf16 As[64][40];
    __shared__ __bf16 Bs[64][40];
    const int tid  = threadIdx.x;
    const int lane = tid & 63;
    const int wid  = tid >> 6;
    const int g    = lane >> 4, l16 = lane & 15;
    const int wr   = wid >> 1,  wc  = wid & 1;
    const int r0   = blockIdx.x * 64;
    const int c0   = blockIdx.y * 64;

    const int sra = tid >> 2, sca = tid & 3;
    const int srb = tid >> 3, scb = tid & 7;

    f32x4 acc[2][2] = {};
    for (int k0 = 0; k0 < 512; k0 += 32) {
        __syncthreads();
        {
            bf16x8 av = *reinterpret_cast<const bf16x8*>(a + (size_t)(r0 + sra) * 512 + k0 + sca * 8);
            *reinterpret_cast<bf16x8*>(&As[sra][sca * 8]) = av;
#pragma unroll
            for (int j = 0; j < 2; ++j) {
                int r = srb + 32 * j;
                float4 bv = *reinterpret_cast<const float4*>(Wm + (size_t)(c0 + r) * 512 + k0 + scb * 4);
                bf16x4 bp = { (__bf16)bv.x, (__bf16)bv.y, (__bf16)bv.z, (__bf16)bv.w };
                *reinterpret_cast<bf16x4*>(&Bs[r][scb * 4]) = bp;
            }
        }
        __syncthreads();
        bf16x8 af[2], bfr[2];
#pragma unroll
        for (int rt = 0; rt < 2; ++rt)
            af[rt] = *reinterpret_cast<const bf16x8*>(&As[wr * 32 + rt * 16 + l16][g * 8]);
#pragma unroll
        for (int ct = 0; ct < 2; ++ct)
            bfr[ct] = *reinterpret_cast<const bf16x8*>(&Bs[wc * 32 + ct * 16 + l16][g * 8]);
#pragma unroll
        for (int rt = 0; rt < 2; ++rt)
#pragma unroll
            for (int ct = 0; ct < 2; ++ct)
                acc[rt][ct] = MFMA16(af[rt], bfr[ct], acc[rt][ct]);
    }

#pragma unroll
    for (int rt = 0; rt < 2; ++rt)
#pragma unroll
        for (int ct = 0; ct < 2; ++ct)
#pragma unroll
            for (int reg = 0; reg < 4; ++reg) {
                int r = r0 + wr * 32 + rt * 16 + 4 * g + reg;
                int c = c0 + wc * 32 + ct * 16 + l16;
                out[(size_t)r * 512 + c] = acc[rt][ct][reg] + bm[c];
            }
}

// ---------------------------------------------------------------------------
extern "C" void kernel_launch(void* const* d_in, const int* in_sizes, int n_in,
                              void* d_out, int out_size, void* d_ws, size_t ws_size,
                              hipStream_t stream)
{
    const float* x    = (const float*)d_in[0];
    const float* bias = (const float*)d_in[1];
    const float* Wq   = (const float*)d_in[2];
    const float* Wk   = (const float*)d_in[3];
    const float* Wv   = (const float*)d_in[4];
    const float* Wm   = (const float*)d_in[5];
    const float* bm   = (const float*)d_in[6];
    float* out = (float*)d_out;

    const size_t SEG = (size_t)8 * 8 * 1024 * 64;   // 4M elems (8 MB bf16) each
    __bf16* qw  = (__bf16*)d_ws;
    __bf16* kw  = qw + SEG;
    __bf16* vtw = kw + SEG;
    __bf16* ow  = vtw + SEG;
    __bf16* bT  = (__bf16*)((char*)d_ws + ((size_t)64 << 20));   // 128 MB

    bias_retile<<<dim3(512), 512, 0, stream>>>(bias, bT);
    gemm_qkv   <<<dim3(128, 24), 256, 0, stream>>>(x, Wq, Wk, Wv, qw, kw, vtw);
    attn_v3    <<<dim3(64, 8), 512, 0, stream>>>(qw, kw, vtw, bT, ow);
    gemm_out   <<<dim3(128, 8), 256, 0, stream>>>(ow, Wm, bm, out);
}

// Round 10
// 157.209 us; speedup vs baseline: 1.9271x; 1.1351x over previous
//
#include <hip/hip_runtime.h>
#include <hip/hip_bf16.h>

typedef __bf16 bf16x8 __attribute__((ext_vector_type(8)));
typedef __bf16 bf16x4 __attribute__((ext_vector_type(4)));
typedef float  f32x4  __attribute__((ext_vector_type(4)));

#define MFMA16(a, b, c) __builtin_amdgcn_mfma_f32_16x16x32_bf16((a), (b), (c), 0, 0, 0)

// LDS-visibility barrier that does NOT drain outstanding global loads.
__device__ __forceinline__ void barrier_lds_only() {
    asm volatile("s_waitcnt lgkmcnt(0)" ::: "memory");
    __builtin_amdgcn_s_barrier();
    __builtin_amdgcn_sched_barrier(0);
}

// Problem constants: B=8, N=1024, D=512, H=8, DH=64

// ---------------------------------------------------------------------------
// Kernel 1: fused QKV projection (unchanged).  q,k: [b][h][n][dh] bf16
// (q pre-scaled); v TRANSPOSED [b][h][dh][n] bf16.
// ---------------------------------------------------------------------------
__global__ __launch_bounds__(256) void gemm_qkv(
    const float* __restrict__ x,
    const float* __restrict__ Wq, const float* __restrict__ Wk,
    const float* __restrict__ Wv,
    __bf16* __restrict__ qo, __bf16* __restrict__ ko, __bf16* __restrict__ vto)
{
    __shared__ __bf16 As[64][40];
    __shared__ __bf16 Bs[64][40];
    const int tid  = threadIdx.x;
    const int lane = tid & 63;
    const int wid  = tid >> 6;
    const int g    = lane >> 4, l16 = lane & 15;
    const int wr   = wid >> 1,  wc  = wid & 1;
    const int r0   = blockIdx.x * 64;
    const int widx = blockIdx.y >> 3;          // 0=q 1=k 2=v
    const int c0   = (blockIdx.y & 7) * 64;
    const float* W = (widx == 0) ? Wq : (widx == 1 ? Wk : Wv);

    const int sr  = tid >> 3;
    const int scq = tid & 7;

    f32x4 acc[2][2] = {};

    for (int k0 = 0; k0 < 512; k0 += 32) {
        __syncthreads();
#pragma unroll
        for (int j = 0; j < 2; ++j) {
            const int r = sr + 32 * j;
            float4 av = *reinterpret_cast<const float4*>(x + (size_t)(r0 + r) * 512 + k0 + scq * 4);
            float4 bv = *reinterpret_cast<const float4*>(W + (size_t)(c0 + r) * 512 + k0 + scq * 4);
            bf16x4 ap = { (__bf16)av.x, (__bf16)av.y, (__bf16)av.z, (__bf16)av.w };
            bf16x4 bp = { (__bf16)bv.x, (__bf16)bv.y, (__bf16)bv.z, (__bf16)bv.w };
            *reinterpret_cast<bf16x4*>(&As[r][scq * 4]) = ap;
            *reinterpret_cast<bf16x4*>(&Bs[r][scq * 4]) = bp;
        }
        __syncthreads();
        bf16x8 af[2], bfr[2];
#pragma unroll
        for (int rt = 0; rt < 2; ++rt)
            af[rt] = *reinterpret_cast<const bf16x8*>(&As[wr * 32 + rt * 16 + l16][g * 8]);
#pragma unroll
        for (int ct = 0; ct < 2; ++ct)
            bfr[ct] = *reinterpret_cast<const bf16x8*>(&Bs[wc * 32 + ct * 16 + l16][g * 8]);
#pragma unroll
        for (int rt = 0; rt < 2; ++rt)
#pragma unroll
            for (int ct = 0; ct < 2; ++ct)
                acc[rt][ct] = MFMA16(af[rt], bfr[ct], acc[rt][ct]);
    }

    if (widx == 2) {
#pragma unroll
        for (int rt = 0; rt < 2; ++rt)
#pragma unroll
            for (int ct = 0; ct < 2; ++ct) {
                int r = r0 + wr * 32 + rt * 16 + 4 * g;
                int c = c0 + wc * 32 + ct * 16 + l16;
                int b = r >> 10, n = r & 1023, h = c >> 6, dh = c & 63;
                bf16x4 pv = { (__bf16)acc[rt][ct][0], (__bf16)acc[rt][ct][1],
                              (__bf16)acc[rt][ct][2], (__bf16)acc[rt][ct][3] };
                *reinterpret_cast<bf16x4*>(vto + (((size_t)b * 8 + h) * 64 + dh) * 1024 + n) = pv;
            }
    } else {
        __bf16* dst = (widx == 0) ? qo : ko;
        const float scale = (widx == 0) ? 0.125f : 1.0f;
#pragma unroll
        for (int rt = 0; rt < 2; ++rt)
#pragma unroll
            for (int ct = 0; ct < 2; ++ct)
#pragma unroll
                for (int reg = 0; reg < 4; ++reg) {
                    int r = r0 + wr * 32 + rt * 16 + 4 * g + reg;
                    int c = c0 + wc * 32 + ct * 16 + l16;
                    float val = acc[rt][ct][reg] * scale;
                    int b = r >> 10, n = r & 1023, h = c >> 6, dh = c & 63;
                    dst[(((size_t)b * 8 + h) * 1024 + n) * 64 + dh] = (__bf16)val;
                }
    }
}

// ---------------------------------------------------------------------------
// Kernel 2: fused flash attention + in-kernel bias transpose.
// Block = 512 thr (8 waves = 8 heads), 32 Q-rows, grid (8 b, 32 nt) ->
// batch b pinned to XCD b (K/V 2MB L2-resident).
// Per m-tile (32 K/V rows):
//   bias[b, n0:32, m0:32, :8] read COALESCED (f32x4, nontemporal), reg-staged
//   one tile ahead, LDS-transposed to bsm[buf][n][h][m] (bf16).
//   K/V staged per-head into LDS with coalesced reads (R8 fix).
//   Fixed-max softmax p = exp(s+bias-16); wave-local psm bounce for PV.
// 2 lgkm-only barriers/iter; global loads stay in flight across both.
// LDS ~129KB -> 1 block/CU.
// ---------------------------------------------------------------------------
__global__ __launch_bounds__(512, 2) void attn_v4(
    const __bf16* __restrict__ qw, const __bf16* __restrict__ kw,
    const __bf16* __restrict__ vtw, const float* __restrict__ bias,
    __bf16* __restrict__ ow)
{
    __shared__ __bf16 Ks[8][32][72];      // [h][m][dh]   36,864 B
    __shared__ __bf16 Vs[8][64][40];      // [h][dh][m]   40,960 B
    __shared__ __bf16 bsm[2][32][8][33];  // [buf][n][h][m] 33,792 B
    __shared__ __bf16 psm[8][32][40];     // per-wave P   20,480 B
    const int tid  = threadIdx.x;
    const int w    = tid >> 6;             // head
    const int lane = tid & 63;
    const int g    = lane >> 4, l16 = lane & 15;
    const int b    = blockIdx.x;
    const int n0   = blockIdx.y * 32;
    const size_t bhs = (size_t)b * 8 + w;

    const __bf16* kbase = kw  + bhs * 1024 * 64;
    const __bf16* vbase = vtw + bhs * 64 * 1024;
    const float*  bias_b = bias + ((size_t)(b * 1024 + n0)) * 8192;

    // staging maps
    const int snr = tid >> 4;     // bias n-row 0..31
    const int sf  = tid & 15;     // bias f32x4 lane base

    // Q fragments (resident): 32 rows -> rf in {0,1}
    bf16x8 qf[2][2];
#pragma unroll
    for (int rf = 0; rf < 2; ++rf)
#pragma unroll
        for (int kc = 0; kc < 2; ++kc)
            qf[rf][kc] = *reinterpret_cast<const bf16x8*>(
                qw + (bhs * 1024 + n0 + rf * 16 + l16) * 64 + kc * 32 + g * 8);

    f32x4 o[2][4] = {};
    float lrun[2][4] = {};

    f32x4  bp[4];
    bf16x8 kp[4], vp[4];

#define LOAD_TILE(tt)                                                          \
    {                                                                          \
        const int m0_ = (tt) * 32;                                             \
        _Pragma("unroll")                                                      \
        for (int c = 0; c < 4; ++c) {                                          \
            bp[c] = __builtin_nontemporal_load(reinterpret_cast<const f32x4*>( \
                bias_b + (size_t)snr * 8192 + m0_ * 8 + (sf + 16 * c) * 4));   \
            const int idx = c * 64 + lane;                                     \
            kp[c] = *reinterpret_cast<const bf16x8*>(                          \
                kbase + (size_t)(m0_ + (idx >> 3)) * 64 + (idx & 7) * 8);      \
            vp[c] = *reinterpret_cast<const bf16x8*>(                          \
                vbase + (size_t)(idx >> 2) * 1024 + m0_ + (idx & 3) * 8);      \
        }                                                                      \
    }

#define WRITE_PEND(buf)                                                        \
    {                                                                          \
        _Pragma("unroll")                                                      \
        for (int c = 0; c < 4; ++c) {                                          \
            const int f4 = sf + 16 * c;                                        \
            const int mm = f4 >> 1, h0 = (f4 & 1) * 4;                         \
            bsm[buf][snr][h0 + 0][mm] = (__bf16)bp[c].x;                       \
            bsm[buf][snr][h0 + 1][mm] = (__bf16)bp[c].y;                       \
            bsm[buf][snr][h0 + 2][mm] = (__bf16)bp[c].z;                       \
            bsm[buf][snr][h0 + 3][mm] = (__bf16)bp[c].w;                       \
            const int idx = c * 64 + lane;                                     \
            *reinterpret_cast<bf16x8*>(&Ks[w][idx >> 3][(idx & 7) * 8]) = kp[c]; \
            *reinterpret_cast<bf16x8*>(&Vs[w][idx >> 2][(idx & 3) * 8]) = vp[c]; \
        }                                                                      \
    }

    // ---- prologue: tile 0 staged directly; pend <- tile 1 ----
    LOAD_TILE(0)
    WRITE_PEND(0)
    LOAD_TILE(1)
    __syncthreads();

    for (int t = 0; t < 32; ++t) {
        const int buf = t & 1;

        // fragments from LDS
        bf16x8 kf[2][2], vf[4];
#pragma unroll
        for (int ct = 0; ct < 2; ++ct)
#pragma unroll
            for (int kc = 0; kc < 2; ++kc)
                kf[ct][kc] = *reinterpret_cast<const bf16x8*>(
                    &Ks[w][ct * 16 + l16][kc * 32 + g * 8]);
#pragma unroll
        for (int oc = 0; oc < 4; ++oc)
            vf[oc] = *reinterpret_cast<const bf16x8*>(&Vs[w][oc * 16 + l16][g * 8]);

        // QK^T  (rf x ct x kc)
        f32x4 s[2][2] = {};
#pragma unroll
        for (int rf = 0; rf < 2; ++rf)
#pragma unroll
            for (int ct = 0; ct < 2; ++ct) {
                s[rf][ct] = MFMA16(qf[rf][0], kf[ct][0], s[rf][ct]);
                s[rf][ct] = MFMA16(qf[rf][1], kf[ct][1], s[rf][ct]);
            }

        // fixed-max softmax with LDS-transposed bias
#pragma unroll
        for (int rf = 0; rf < 2; ++rf)
#pragma unroll
            for (int reg = 0; reg < 4; ++reg) {
                const int nr = rf * 16 + 4 * g + reg;
                float b0 = (float)bsm[buf][nr][w][l16];
                float b1 = (float)bsm[buf][nr][w][16 + l16];
                float p0 = __expf(s[rf][0][reg] + b0 - 16.0f);
                float p1 = __expf(s[rf][1][reg] + b1 - 16.0f);
                lrun[rf][reg] += p0 + p1;
                psm[w][nr][l16]      = (__bf16)p0;
                psm[w][nr][16 + l16] = (__bf16)p1;
            }

        // wave-local P relayout + PV
        bf16x8 pf[2];
#pragma unroll
        for (int rf = 0; rf < 2; ++rf)
            pf[rf] = *reinterpret_cast<const bf16x8*>(&psm[w][rf * 16 + l16][g * 8]);
#pragma unroll
        for (int rf = 0; rf < 2; ++rf)
#pragma unroll
            for (int oc = 0; oc < 4; ++oc)
                o[rf][oc] = MFMA16(pf[rf], vf[oc], o[rf][oc]);

        barrier_lds_only();              // all waves done reading tile t

        WRITE_PEND((t + 1) & 1)          // tile t+1 (loads issued 1 iter ago)
        {
            const int tn = (t + 2 < 32) ? t + 2 : 31;
            LOAD_TILE(tn)                // in flight across next barrier
        }

        barrier_lds_only();              // tile t+1 visible
    }
#undef LOAD_TILE
#undef WRITE_PEND

    // epilogue: denominator across the 16 m-lanes
#pragma unroll
    for (int rf = 0; rf < 2; ++rf)
#pragma unroll
        for (int reg = 0; reg < 4; ++reg) {
            float l = lrun[rf][reg];
            l += __shfl_xor(l, 1);
            l += __shfl_xor(l, 2);
            l += __shfl_xor(l, 4);
            l += __shfl_xor(l, 8);
            lrun[rf][reg] = l;
        }

#pragma unroll
    for (int rf = 0; rf < 2; ++rf)
#pragma unroll
        for (int oc = 0; oc < 4; ++oc)
#pragma unroll
            for (int reg = 0; reg < 4; ++reg) {
                int n  = n0 + rf * 16 + 4 * g + reg;
                int dh = oc * 16 + l16;
                float val = o[rf][oc][reg] / lrun[rf][reg];
                ow[((size_t)b * 1024 + n) * 512 + w * 64 + dh] = (__bf16)val;
            }
}

// ---------------------------------------------------------------------------
// Kernel 3: output projection (unchanged).
// ---------------------------------------------------------------------------
__global__ __launch_bounds__(256) void gemm_out(
    const __bf16* __restrict__ a, const float* __restrict__ Wm,
    const float* __restrict__ bm, float* __restrict__ out)
{
    __shared__ __bf16 As[64][40];
    __shared__ __bf16 Bs[64][40];
    const int tid  = threadIdx.x;
    const int lane = tid & 63;
    const int wid  = tid >> 6;
    const int g    = lane >> 4, l16 = lane & 15;
    const int wr   = wid >> 1,  wc  = wid & 1;
    const int r0   = blockIdx.x * 64;
    const int c0   = blockIdx.y * 64;

    const int sra = tid >> 2, sca = tid & 3;
    const int srb = tid >> 3, scb = tid & 7;

    f32x4 acc[2][2] = {};
    for (int k0 = 0; k0 < 512; k0 += 32) {
        __syncthreads();
        {
            bf16x8 av = *reinterpret_cast<const bf16x8*>(a + (size_t)(r0 + sra) * 512 + k0 + sca * 8);
            *reinterpret_cast<bf16x8*>(&As[sra][sca * 8]) = av;
#pragma unroll
            for (int j = 0; j < 2; ++j) {
                int r = srb + 32 * j;
                float4 bv = *reinterpret_cast<const float4*>(Wm + (size_t)(c0 + r) * 512 + k0 + scb * 4);
                bf16x4 bp = { (__bf16)bv.x, (__bf16)bv.y, (__bf16)bv.z, (__bf16)bv.w };
                *reinterpret_cast<bf16x4*>(&Bs[r][scb * 4]) = bp;
            }
        }
        __syncthreads();
        bf16x8 af[2], bfr[2];
#pragma unroll
        for (int rt = 0; rt < 2; ++rt)
            af[rt] = *reinterpret_cast<const bf16x8*>(&As[wr * 32 + rt * 16 + l16][g * 8]);
#pragma unroll
        for (int ct = 0; ct < 2; ++ct)
            bfr[ct] = *reinterpret_cast<const bf16x8*>(&Bs[wc * 32 + ct * 16 + l16][g * 8]);
#pragma unroll
        for (int rt = 0; rt < 2; ++rt)
#pragma unroll
            for (int ct = 0; ct < 2; ++ct)
                acc[rt][ct] = MFMA16(af[rt], bfr[ct], acc[rt][ct]);
    }

#pragma unroll
    for (int rt = 0; rt < 2; ++rt)
#pragma unroll
        for (int ct = 0; ct < 2; ++ct)
#pragma unroll
            for (int reg = 0; reg < 4; ++reg) {
                int r = r0 + wr * 32 + rt * 16 + 4 * g + reg;
                int c = c0 + wc * 32 + ct * 16 + l16;
                out[(size_t)r * 512 + c] = acc[rt][ct][reg] + bm[c];
            }
}

// ---------------------------------------------------------------------------
extern "C" void kernel_launch(void* const* d_in, const int* in_sizes, int n_in,
                              void* d_out, int out_size, void* d_ws, size_t ws_size,
                              hipStream_t stream)
{
    const float* x    = (const float*)d_in[0];
    const float* bias = (const float*)d_in[1];
    const float* Wq   = (const float*)d_in[2];
    const float* Wk   = (const float*)d_in[3];
    const float* Wv   = (const float*)d_in[4];
    const float* Wm   = (const float*)d_in[5];
    const float* bm   = (const float*)d_in[6];
    float* out = (float*)d_out;

    const size_t SEG = (size_t)8 * 8 * 1024 * 64;   // 4M elems (8 MB bf16) each
    __bf16* qw  = (__bf16*)d_ws;
    __bf16* kw  = qw + SEG;
    __bf16* vtw = kw + SEG;
    __bf16* ow  = vtw + SEG;

    gemm_qkv<<<dim3(128, 24), 256, 0, stream>>>(x, Wq, Wk, Wv, qw, kw, vtw);
    attn_v4 <<<dim3(8, 32), 512, 0, stream>>>(qw, kw, vtw, bias, ow);
    gemm_out<<<dim3(128, 8), 256, 0, stream>>>(ow, Wm, bm, out);
}

// Round 11
// 149.433 us; speedup vs baseline: 2.0274x; 1.0520x over previous
//
#include <hip/hip_runtime.h>
#include <hip/hip_bf16.h>

typedef __bf16 bf16x8 __attribute__((ext_vector_type(8)));
typedef __bf16 bf16x4 __attribute__((ext_vector_type(4)));
typedef float  f32x4  __attribute__((ext_vector_type(4)));

#define MFMA16(a, b, c) __builtin_amdgcn_mfma_f32_16x16x32_bf16((a), (b), (c), 0, 0, 0)

// LDS-visibility barrier that does NOT drain outstanding global loads.
__device__ __forceinline__ void barrier_lds_only() {
    asm volatile("s_waitcnt lgkmcnt(0)" ::: "memory");
    __builtin_amdgcn_s_barrier();
    __builtin_amdgcn_sched_barrier(0);
}

// Problem constants: B=8, N=1024, D=512, H=8, DH=64

// ---------------------------------------------------------------------------
// Kernel 1: fused QKV projection (unchanged).
// ---------------------------------------------------------------------------
__global__ __launch_bounds__(256) void gemm_qkv(
    const float* __restrict__ x,
    const float* __restrict__ Wq, const float* __restrict__ Wk,
    const float* __restrict__ Wv,
    __bf16* __restrict__ qo, __bf16* __restrict__ ko, __bf16* __restrict__ vto)
{
    __shared__ __bf16 As[64][40];
    __shared__ __bf16 Bs[64][40];
    const int tid  = threadIdx.x;
    const int lane = tid & 63;
    const int wid  = tid >> 6;
    const int g    = lane >> 4, l16 = lane & 15;
    const int wr   = wid >> 1,  wc  = wid & 1;
    const int r0   = blockIdx.x * 64;
    const int widx = blockIdx.y >> 3;          // 0=q 1=k 2=v
    const int c0   = (blockIdx.y & 7) * 64;
    const float* W = (widx == 0) ? Wq : (widx == 1 ? Wk : Wv);

    const int sr  = tid >> 3;
    const int scq = tid & 7;

    f32x4 acc[2][2] = {};

    for (int k0 = 0; k0 < 512; k0 += 32) {
        __syncthreads();
#pragma unroll
        for (int j = 0; j < 2; ++j) {
            const int r = sr + 32 * j;
            float4 av = *reinterpret_cast<const float4*>(x + (size_t)(r0 + r) * 512 + k0 + scq * 4);
            float4 bv = *reinterpret_cast<const float4*>(W + (size_t)(c0 + r) * 512 + k0 + scq * 4);
            bf16x4 ap = { (__bf16)av.x, (__bf16)av.y, (__bf16)av.z, (__bf16)av.w };
            bf16x4 bp = { (__bf16)bv.x, (__bf16)bv.y, (__bf16)bv.z, (__bf16)bv.w };
            *reinterpret_cast<bf16x4*>(&As[r][scq * 4]) = ap;
            *reinterpret_cast<bf16x4*>(&Bs[r][scq * 4]) = bp;
        }
        __syncthreads();
        bf16x8 af[2], bfr[2];
#pragma unroll
        for (int rt = 0; rt < 2; ++rt)
            af[rt] = *reinterpret_cast<const bf16x8*>(&As[wr * 32 + rt * 16 + l16][g * 8]);
#pragma unroll
        for (int ct = 0; ct < 2; ++ct)
            bfr[ct] = *reinterpret_cast<const bf16x8*>(&Bs[wc * 32 + ct * 16 + l16][g * 8]);
#pragma unroll
        for (int rt = 0; rt < 2; ++rt)
#pragma unroll
            for (int ct = 0; ct < 2; ++ct)
                acc[rt][ct] = MFMA16(af[rt], bfr[ct], acc[rt][ct]);
    }

    if (widx == 2) {
#pragma unroll
        for (int rt = 0; rt < 2; ++rt)
#pragma unroll
            for (int ct = 0; ct < 2; ++ct) {
                int r = r0 + wr * 32 + rt * 16 + 4 * g;
                int c = c0 + wc * 32 + ct * 16 + l16;
                int b = r >> 10, n = r & 1023, h = c >> 6, dh = c & 63;
                bf16x4 pv = { (__bf16)acc[rt][ct][0], (__bf16)acc[rt][ct][1],
                              (__bf16)acc[rt][ct][2], (__bf16)acc[rt][ct][3] };
                *reinterpret_cast<bf16x4*>(vto + (((size_t)b * 8 + h) * 64 + dh) * 1024 + n) = pv;
            }
    } else {
        __bf16* dst = (widx == 0) ? qo : ko;
        const float scale = (widx == 0) ? 0.125f : 1.0f;
#pragma unroll
        for (int rt = 0; rt < 2; ++rt)
#pragma unroll
            for (int ct = 0; ct < 2; ++ct)
#pragma unroll
                for (int reg = 0; reg < 4; ++reg) {
                    int r = r0 + wr * 32 + rt * 16 + 4 * g + reg;
                    int c = c0 + wc * 32 + ct * 16 + l16;
                    float val = acc[rt][ct][reg] * scale;
                    int b = r >> 10, n = r & 1023, h = c >> 6, dh = c & 63;
                    dst[(((size_t)b * 8 + h) * 1024 + n) * 64 + dh] = (__bf16)val;
                }
    }
}

// ---------------------------------------------------------------------------
// Kernel 2: fused flash attention + in-kernel bias transpose.
// R11: bias pend registers 2-DEEP (A/B, static indexing) -> each bias load
// covered by ~2 compute phases (> HBM service+latency); K/V 1-deep (L2).
// ONE lgkm-only barrier per iter (bsm double-buffered; K/V/psm wave-local).
// ---------------------------------------------------------------------------
__global__ __launch_bounds__(512, 2) void attn_v5(
    const __bf16* __restrict__ qw, const __bf16* __restrict__ kw,
    const __bf16* __restrict__ vtw, const float* __restrict__ bias,
    __bf16* __restrict__ ow)
{
    __shared__ __bf16 Ks[8][32][72];      // [h][m][dh]   wave-local
    __shared__ __bf16 Vs[8][64][40];      // [h][dh][m]   wave-local
    __shared__ __bf16 bsm[2][32][8][33];  // [buf][n][h][m] cross-wave
    __shared__ __bf16 psm[8][32][40];     // wave-local P bounce
    const int tid  = threadIdx.x;
    const int w    = tid >> 6;             // head
    const int lane = tid & 63;
    const int g    = lane >> 4, l16 = lane & 15;
    const int b    = blockIdx.x;
    const int n0   = blockIdx.y * 32;
    const size_t bhs = (size_t)b * 8 + w;

    const __bf16* kbase = kw  + bhs * 1024 * 64;
    const __bf16* vbase = vtw + bhs * 64 * 1024;
    const float*  bias_b = bias + ((size_t)(b * 1024 + n0)) * 8192;

    const int snr = tid >> 4;     // bias n-row 0..31
    const int sf  = tid & 15;     // bias f32x4 lane base

    bf16x8 qf[2][2];
#pragma unroll
    for (int rf = 0; rf < 2; ++rf)
#pragma unroll
        for (int kc = 0; kc < 2; ++kc)
            qf[rf][kc] = *reinterpret_cast<const bf16x8*>(
                qw + (bhs * 1024 + n0 + rf * 16 + l16) * 64 + kc * 32 + g * 8);

    f32x4 o[2][4] = {};
    float lrun[2][4] = {};

    f32x4  bpA[4], bpB[4];
    bf16x8 kp[4], vp[4];

#define LOAD_BIAS(dst, tt)                                                     \
    {                                                                          \
        const int m0_ = (tt) * 32;                                             \
        _Pragma("unroll")                                                      \
        for (int c = 0; c < 4; ++c)                                            \
            dst[c] = __builtin_nontemporal_load(reinterpret_cast<const f32x4*>(\
                bias_b + (size_t)snr * 8192 + m0_ * 8 + (sf + 16 * c) * 4));   \
    }

#define LOAD_KV(tt)                                                            \
    {                                                                          \
        const int m0_ = (tt) * 32;                                             \
        _Pragma("unroll")                                                      \
        for (int c = 0; c < 4; ++c) {                                          \
            const int idx = c * 64 + lane;                                     \
            kp[c] = *reinterpret_cast<const bf16x8*>(                          \
                kbase + (size_t)(m0_ + (idx >> 3)) * 64 + (idx & 7) * 8);      \
            vp[c] = *reinterpret_cast<const bf16x8*>(                          \
                vbase + (size_t)(idx >> 2) * 1024 + m0_ + (idx & 3) * 8);      \
        }                                                                      \
    }

#define WRITE_BIAS(buf, src)                                                   \
    {                                                                          \
        _Pragma("unroll")                                                      \
        for (int c = 0; c < 4; ++c) {                                          \
            const int f4 = sf + 16 * c;                                        \
            const int mm = f4 >> 1, h0 = (f4 & 1) * 4;                         \
            bsm[buf][snr][h0 + 0][mm] = (__bf16)src[c].x;                      \
            bsm[buf][snr][h0 + 1][mm] = (__bf16)src[c].y;                      \
            bsm[buf][snr][h0 + 2][mm] = (__bf16)src[c].z;                      \
            bsm[buf][snr][h0 + 3][mm] = (__bf16)src[c].w;                      \
        }                                                                      \
    }

#define WRITE_KV()                                                             \
    {                                                                          \
        _Pragma("unroll")                                                      \
        for (int c = 0; c < 4; ++c) {                                          \
            const int idx = c * 64 + lane;                                     \
            *reinterpret_cast<bf16x8*>(&Ks[w][idx >> 3][(idx & 7) * 8]) = kp[c]; \
            *reinterpret_cast<bf16x8*>(&Vs[w][idx >> 2][(idx & 3) * 8]) = vp[c]; \
        }                                                                      \
    }

    // STEP: compute tile t from Ks/Vs + bsm[BUF]; write tile t+1 (bias from
    // bpX loaded 2 iters ago, K/V from kp/vp loaded 1 iter ago); refill.
#define ATTN_STEP(t, BUF, bpX)                                                 \
    {                                                                          \
        bf16x8 kf[2][2], vf[4];                                                \
        _Pragma("unroll")                                                      \
        for (int ct = 0; ct < 2; ++ct)                                         \
            _Pragma("unroll")                                                  \
            for (int kc = 0; kc < 2; ++kc)                                     \
                kf[ct][kc] = *reinterpret_cast<const bf16x8*>(                 \
                    &Ks[w][ct * 16 + l16][kc * 32 + g * 8]);                   \
        _Pragma("unroll")                                                      \
        for (int oc = 0; oc < 4; ++oc)                                         \
            vf[oc] = *reinterpret_cast<const bf16x8*>(&Vs[w][oc * 16 + l16][g * 8]); \
        f32x4 s[2][2] = {};                                                    \
        _Pragma("unroll")                                                      \
        for (int rf = 0; rf < 2; ++rf)                                         \
            _Pragma("unroll")                                                  \
            for (int ct = 0; ct < 2; ++ct) {                                   \
                s[rf][ct] = MFMA16(qf[rf][0], kf[ct][0], s[rf][ct]);           \
                s[rf][ct] = MFMA16(qf[rf][1], kf[ct][1], s[rf][ct]);           \
            }                                                                  \
        _Pragma("unroll")                                                      \
        for (int rf = 0; rf < 2; ++rf)                                         \
            _Pragma("unroll")                                                  \
            for (int reg = 0; reg < 4; ++reg) {                                \
                const int nr = rf * 16 + 4 * g + reg;                          \
                float b0 = (float)bsm[BUF][nr][w][l16];                        \
                float b1 = (float)bsm[BUF][nr][w][16 + l16];                   \
                float p0 = __expf(s[rf][0][reg] + b0 - 16.0f);                 \
                float p1 = __expf(s[rf][1][reg] + b1 - 16.0f);                 \
                lrun[rf][reg] += p0 + p1;                                      \
                psm[w][nr][l16]      = (__bf16)p0;                             \
                psm[w][nr][16 + l16] = (__bf16)p1;                             \
            }                                                                  \
        bf16x8 pf[2];                                                          \
        _Pragma("unroll")                                                      \
        for (int rf = 0; rf < 2; ++rf)                                         \
            pf[rf] = *reinterpret_cast<const bf16x8*>(&psm[w][rf * 16 + l16][g * 8]); \
        _Pragma("unroll")                                                      \
        for (int rf = 0; rf < 2; ++rf)                                         \
            _Pragma("unroll")                                                  \
            for (int oc = 0; oc < 4; ++oc)                                     \
                o[rf][oc] = MFMA16(pf[rf], vf[oc], o[rf][oc]);                 \
        /* stage tile t+1 (counted vmcnt: other bias set stays in flight) */   \
        WRITE_BIAS((BUF) ^ 1, bpX)                                             \
        WRITE_KV()                                                             \
        /* refill: K/V <- t+2 (1-deep, L2), bias bpX <- t+3 (2-deep, HBM) */   \
        LOAD_KV((t) + 2 < 32 ? (t) + 2 : 31)                                   \
        LOAD_BIAS(bpX, (t) + 3 < 32 ? (t) + 3 : 31)                            \
        barrier_lds_only();                                                    \
    }

    // ---- prologue ----
    LOAD_KV(0)
    LOAD_BIAS(bpA, 0)
    WRITE_BIAS(0, bpA)
    WRITE_KV()
    LOAD_KV(1)
    LOAD_BIAS(bpA, 1)
    LOAD_BIAS(bpB, 2)
    __syncthreads();

    for (int t = 0; t < 32; t += 2) {
        ATTN_STEP(t,     0, bpA)
        ATTN_STEP(t + 1, 1, bpB)
    }
#undef ATTN_STEP
#undef LOAD_BIAS
#undef LOAD_KV
#undef WRITE_BIAS
#undef WRITE_KV

    // epilogue: denominator across the 16 m-lanes
#pragma unroll
    for (int rf = 0; rf < 2; ++rf)
#pragma unroll
        for (int reg = 0; reg < 4; ++reg) {
            float l = lrun[rf][reg];
            l += __shfl_xor(l, 1);
            l += __shfl_xor(l, 2);
            l += __shfl_xor(l, 4);
            l += __shfl_xor(l, 8);
            lrun[rf][reg] = l;
        }

#pragma unroll
    for (int rf = 0; rf < 2; ++rf)
#pragma unroll
        for (int oc = 0; oc < 4; ++oc)
#pragma unroll
            for (int reg = 0; reg < 4; ++reg) {
                int n  = n0 + rf * 16 + 4 * g + reg;
                int dh = oc * 16 + l16;
                float val = o[rf][oc][reg] / lrun[rf][reg];
                ow[((size_t)b * 1024 + n) * 512 + w * 64 + dh] = (__bf16)val;
            }
}

// ---------------------------------------------------------------------------
// Kernel 3: output projection (unchanged).
// ---------------------------------------------------------------------------
__global__ __launch_bounds__(256) void gemm_out(
    const __bf16* __restrict__ a, const float* __restrict__ Wm,
    const float* __restrict__ bm, float* __restrict__ out)
{
    __shared__ __bf16 As[64][40];
    __shared__ __bf16 Bs[64][40];
    const int tid  = threadIdx.x;
    const int lane = tid & 63;
    const int wid  = tid >> 6;
    const int g    = lane >> 4, l16 = lane & 15;
    const int wr   = wid >> 1,  wc  = wid & 1;
    const int r0   = blockIdx.x * 64;
    const int c0   = blockIdx.y * 64;

    const int sra = tid >> 2, sca = tid & 3;
    const int srb = tid >> 3, scb = tid & 7;

    f32x4 acc[2][2] = {};
    for (int k0 = 0; k0 < 512; k0 += 32) {
        __syncthreads();
        {
            bf16x8 av = *reinterpret_cast<const bf16x8*>(a + (size_t)(r0 + sra) * 512 + k0 + sca * 8);
            *reinterpret_cast<bf16x8*>(&As[sra][sca * 8]) = av;
#pragma unroll
            for (int j = 0; j < 2; ++j) {
                int r = srb + 32 * j;
                float4 bv = *reinterpret_cast<const float4*>(Wm + (size_t)(c0 + r) * 512 + k0 + scb * 4);
                bf16x4 bp = { (__bf16)bv.x, (__bf16)bv.y, (__bf16)bv.z, (__bf16)bv.w };
                *reinterpret_cast<bf16x4*>(&Bs[r][scb * 4]) = bp;
            }
        }
        __syncthreads();
        bf16x8 af[2], bfr[2];
#pragma unroll
        for (int rt = 0; rt < 2; ++rt)
            af[rt] = *reinterpret_cast<const bf16x8*>(&As[wr * 32 + rt * 16 + l16][g * 8]);
#pragma unroll
        for (int ct = 0; ct < 2; ++ct)
            bfr[ct] = *reinterpret_cast<const bf16x8*>(&Bs[wc * 32 + ct * 16 + l16][g * 8]);
#pragma unroll
        for (int rt = 0; rt < 2; ++rt)
#pragma unroll
            for (int ct = 0; ct < 2; ++ct)
                acc[rt][ct] = MFMA16(af[rt], bfr[ct], acc[rt][ct]);
    }

#pragma unroll
    for (int rt = 0; rt < 2; ++rt)
#pragma unroll
        for (int ct = 0; ct < 2; ++ct)
#pragma unroll
            for (int reg = 0; reg < 4; ++reg) {
                int r = r0 + wr * 32 + rt * 16 + 4 * g + reg;
                int c = c0 + wc * 32 + ct * 16 + l16;
                out[(size_t)r * 512 + c] = acc[rt][ct][reg] + bm[c];
            }
}

// ---------------------------------------------------------------------------
extern "C" void kernel_launch(void* const* d_in, const int* in_sizes, int n_in,
                              void* d_out, int out_size, void* d_ws, size_t ws_size,
                              hipStream_t stream)
{
    const float* x    = (const float*)d_in[0];
    const float* bias = (const float*)d_in[1];
    const float* Wq   = (const float*)d_in[2];
    const float* Wk   = (const float*)d_in[3];
    const float* Wv   = (const float*)d_in[4];
    const float* Wm   = (const float*)d_in[5];
    const float* bm   = (const float*)d_in[6];
    float* out = (float*)d_out;

    const size_t SEG = (size_t)8 * 8 * 1024 * 64;   // 4M elems (8 MB bf16) each
    __bf16* qw  = (__bf16*)d_ws;
    __bf16* kw  = qw + SEG;
    __bf16* vtw = kw + SEG;
    __bf16* ow  = vtw + SEG;

    gemm_qkv<<<dim3(128, 24), 256, 0, stream>>>(x, Wq, Wk, Wv, qw, kw, vtw);
    attn_v5 <<<dim3(8, 32), 512, 0, stream>>>(qw, kw, vtw, bias, ow);
    gemm_out<<<dim3(128, 8), 256, 0, stream>>>(ow, Wm, bm, out);
}